// Round 7
// baseline (366.547 us; speedup 1.0000x reference)
//
#include <hip/hip_runtime.h>
#include <hip/hip_bf16.h>

#define S_LEN  2048
#define BATCH  2
#define NH     16
#define HD     128
#define HIDDEN 2048
#define MROWS  (BATCH*S_LEN)   // 4096

typedef __attribute__((ext_vector_type(8))) short bf16x8;
typedef __attribute__((ext_vector_type(4))) short s16x4;
typedef __attribute__((ext_vector_type(4))) float f32x4;

__device__ __forceinline__ float bf2f(short s) {
    union { float f; unsigned int u; } v;
    v.u = ((unsigned int)(unsigned short)s) << 16;
    return v.f;
}
__device__ __forceinline__ short f2bf(float f) {
    union { float f; unsigned int u; } v;
    v.f = f;
    unsigned int r = v.u + 0x7fffu + ((v.u >> 16) & 1u);   // RNE, inputs never NaN
    return (short)(r >> 16);
}
__device__ __forceinline__ f32x4 mfma16(bf16x8 a, bf16x8 b, f32x4 c) {
    return __builtin_amdgcn_mfma_f32_16x16x32_bf16(a, b, c, 0, 0, 0);
}
__device__ __forceinline__ void gload16(const void* g, void* l) {
    __builtin_amdgcn_global_load_lds(
        (const __attribute__((address_space(1))) void*)g,
        (__attribute__((address_space(3))) void*)l, 16, 0, 0);
}
#define SBAR()  asm volatile("s_barrier" ::: "memory")
#define LGKM0() do { asm volatile("s_waitcnt lgkmcnt(0)" ::: "memory"); \
                     __builtin_amdgcn_sched_barrier(0); } while (0)

// ---------------------------------------------------------------------------
// Cast fp32 -> bf16: hidden (2 x 4M segs), wq, wk, wv, wo (1 seg each).
// ---------------------------------------------------------------------------
#define SEG (4194304)
__global__ void cast_k(const float* hs, const float* wq, const float* wk,
                       const float* wv, const float* wo, short* dst)
{
    size_t i = ((size_t)blockIdx.x * 256 + threadIdx.x) * 8;
    int seg = (int)(i >> 22);
    const float* s;
    size_t off;
    if (seg < 2)      { s = hs; off = i; }
    else if (seg == 2){ s = wq; off = i - 2 * (size_t)SEG; }
    else if (seg == 3){ s = wk; off = i - 3 * (size_t)SEG; }
    else if (seg == 4){ s = wv; off = i - 4 * (size_t)SEG; }
    else              { s = wo; off = i - 5 * (size_t)SEG; }
    f32x4 lo = *(const f32x4*)(s + off);
    f32x4 hi = *(const f32x4*)(s + off + 4);
    short v[8];
#pragma unroll
    for (int j = 0; j < 4; ++j) { v[j] = f2bf(lo[j]); v[4 + j] = f2bf(hi[j]); }
    *(bf16x8*)(dst + i) = *(bf16x8*)v;
}

// ---------------------------------------------------------------------------
// 8-phase GEMM (m201-template port): C[M][N] = A[M][K] * W[N][K]^T, bf16.
// BM=256, BN=128, K staged in halves of 32 into 4 LDS slots (96 KB).
// 512 threads = 8 waves (4M x 2N), per-wave 64x64 output.
// Counted vmcnt(6) (never 0 in steady state), raw s_barrier, setprio.
// LDS lines: 2 rows x 32k packed into 64 elems; 16B chunk ^= (line&7).
// MODE 0: W in {wq,wk,wv}; C bf16 -> Q/K [bh][s][d], V transposed [bh][d][s]
// MODE 1: W = wo; C fp32 [M][N]
// ---------------------------------------------------------------------------
template<int MODE>
__global__ __launch_bounds__(512, 1)
void gemm8p(const short* A, const short* W0, const short* W1, const short* W2,
            short* Oq, short* Ok, short* Ov, float* Of)
{
    __shared__ short lds[49152];   // 96 KB: A slots @0 (4x16KB), B slots @64KB (4x8KB)

    const int tid  = threadIdx.x;
    const int lane = tid & 63;
    const int wv   = tid >> 6;          // 0..7
    const int wr   = wv & 3, wc = wv >> 2;
    const int fr   = lane & 15, fg = lane >> 4;

    const int mt = blockIdx.x;
    int nt = blockIdx.y;
    const short* W = W0;
    short* Ob = Oq;
    int osel = 0;
    if (MODE == 0) {
        osel = nt >> 4; nt &= 15;
        W  = (osel == 0) ? W0 : (osel == 1) ? W1 : W2;
        Ob = (osel == 0) ? Oq : (osel == 1) ? Ok : Ov;
    }
    const int row0 = mt * 256, col0 = nt * 128;

    // ---- staging (3 gload16/thread/half: 2 A + 1 B), linear LDS dest,
    //      pre-swizzled global source ----
#define STAGEH(hh)                                                              \
    do {                                                                        \
        const int sl_ = (hh) & 3;                                               \
        const int kg_ = (hh) * 32;                                              \
        _Pragma("unroll")                                                       \
        for (int it_ = 0; it_ < 2; ++it_) {                                     \
            int c_ = it_ * 512 + tid;                                           \
            int ln_ = c_ >> 3;                                                  \
            int cr_ = (c_ & 7) ^ (ln_ & 7);                                     \
            int sr_ = 2 * ln_ + (cr_ >> 2);                                     \
            int sk_ = (cr_ & 3) * 8;                                            \
            gload16(A + (size_t)(row0 + sr_) * HIDDEN + kg_ + sk_,              \
                    (char*)lds + sl_ * 16384 + c_ * 16);                        \
        }                                                                       \
        {                                                                       \
            int c_ = tid;                                                       \
            int ln_ = c_ >> 3;                                                  \
            int cr_ = (c_ & 7) ^ (ln_ & 7);                                     \
            int sr_ = 2 * ln_ + (cr_ >> 2);                                     \
            int sk_ = (cr_ & 3) * 8;                                            \
            gload16(W + (size_t)(col0 + sr_) * HIDDEN + kg_ + sk_,              \
                    (char*)lds + 65536 + sl_ * 8192 + c_ * 16);                 \
        }                                                                       \
    } while (0)

    // LDS reads: row r, k-chunk kc (0..3)
    auto ldsA = [&](int sl, int r, int kc) -> bf16x8 {
        int ln = r >> 1;
        int cs = (((r & 1) << 2) + kc) ^ (ln & 7);
        return *(const bf16x8*)((const char*)lds + sl * 16384 + ln * 128 + cs * 16);
    };
    auto ldsB = [&](int sl, int r, int kc) -> bf16x8 {
        int ln = r >> 1;
        int cs = (((r & 1) << 2) + kc) ^ (ln & 7);
        return *(const bf16x8*)((const char*)lds + 65536 + sl * 8192 + ln * 128 + cs * 16);
    };

    f32x4 acc[4][4];
#pragma unroll
    for (int m = 0; m < 4; ++m)
#pragma unroll
        for (int n = 0; n < 4; ++n) acc[m][n] = (f32x4){0.f, 0.f, 0.f, 0.f};

    // prologue: stage halves 0..2, wait for half 0 (9 issued, keep 6 in flight)
    STAGEH(0); STAGEH(1); STAGEH(2);
    asm volatile("s_waitcnt vmcnt(6)" ::: "memory");
    SBAR();

#pragma unroll 1
    for (int h = 0; h < 64; ++h) {
        const int sl = h & 3;
        // ---- phase 0: read b0..b3, a0,a1; prefetch half h+3; MFMA rows 0,1 --
        bf16x8 b0 = ldsB(sl, wc * 64 +  0 + fr, fg);
        bf16x8 b1 = ldsB(sl, wc * 64 + 16 + fr, fg);
        bf16x8 b2 = ldsB(sl, wc * 64 + 32 + fr, fg);
        bf16x8 b3 = ldsB(sl, wc * 64 + 48 + fr, fg);
        bf16x8 a0 = ldsA(sl, wr * 64 +  0 + fr, fg);
        bf16x8 a1 = ldsA(sl, wr * 64 + 16 + fr, fg);
        if (h + 3 < 64) STAGEH(h + 3);
        SBAR();
        LGKM0();
        __builtin_amdgcn_s_setprio(1);
        acc[0][0] = mfma16(a0, b0, acc[0][0]);
        acc[0][1] = mfma16(a0, b1, acc[0][1]);
        acc[0][2] = mfma16(a0, b2, acc[0][2]);
        acc[0][3] = mfma16(a0, b3, acc[0][3]);
        acc[1][0] = mfma16(a1, b0, acc[1][0]);
        acc[1][1] = mfma16(a1, b1, acc[1][1]);
        acc[1][2] = mfma16(a1, b2, acc[1][2]);
        acc[1][3] = mfma16(a1, b3, acc[1][3]);
        __builtin_amdgcn_s_setprio(0);
        SBAR();
        // ---- phase 1: read a2,a3; MFMA rows 2,3; boundary vmcnt ----
        bf16x8 a2 = ldsA(sl, wr * 64 + 32 + fr, fg);
        bf16x8 a3 = ldsA(sl, wr * 64 + 48 + fr, fg);
        SBAR();
        LGKM0();
        __builtin_amdgcn_s_setprio(1);
        acc[2][0] = mfma16(a2, b0, acc[2][0]);
        acc[2][1] = mfma16(a2, b1, acc[2][1]);
        acc[2][2] = mfma16(a2, b2, acc[2][2]);
        acc[2][3] = mfma16(a2, b3, acc[2][3]);
        acc[3][0] = mfma16(a3, b0, acc[3][0]);
        acc[3][1] = mfma16(a3, b1, acc[3][1]);
        acc[3][2] = mfma16(a3, b2, acc[3][2]);
        acc[3][3] = mfma16(a3, b3, acc[3][3]);
        __builtin_amdgcn_s_setprio(0);
        if (h < 61) asm volatile("s_waitcnt vmcnt(6)" ::: "memory");
        else        asm volatile("s_waitcnt vmcnt(0)" ::: "memory");
        SBAR();
    }
#undef STAGEH

    // ---- epilogue ----
    if (MODE == 0 && osel == 2) {
        // V: transpose 256x128 tile through LDS (reuse staging), store [bh][d][s]
#pragma unroll
        for (int m = 0; m < 4; ++m)
#pragma unroll
            for (int j = 0; j < 4; ++j) {
                int row = wr * 64 + m * 16 + fg * 4 + j;   // s in tile (0..255)
#pragma unroll
                for (int n = 0; n < 4; ++n) {
                    int col = wc * 64 + n * 16 + fr;       // d (0..127)
                    lds[col * 256 + (((row >> 3) ^ (col & 31)) * 8) + (row & 7)] =
                        f2bf(acc[m][n][j]);
                }
            }
        __syncthreads();
        const int b_ = row0 >> 11;
        const int bh = b_ * NH + nt;
        const int s0 = row0 & (S_LEN - 1);
#pragma unroll
        for (int it = 0; it < 8; ++it) {
            int c = it * 512 + tid;                 // 0..4095
            int d = c >> 5, sc = c & 31;
            bf16x8 vv = *(const bf16x8*)&lds[d * 256 + ((sc ^ (d & 31)) * 8)];
            *(bf16x8*)(Ov + ((size_t)bh * HD + d) * S_LEN + s0 + sc * 8) = vv;
        }
    } else {
#pragma unroll
        for (int m = 0; m < 4; ++m)
#pragma unroll
            for (int j = 0; j < 4; ++j) {
                int mrow = row0 + wr * 64 + m * 16 + fg * 4 + j;
#pragma unroll
                for (int n = 0; n < 4; ++n) {
                    int col = col0 + wc * 64 + n * 16 + fr;
                    float val = acc[m][n][j];
                    if (MODE == 0) {
                        int b_ = mrow >> 11, s = mrow & (S_LEN - 1);
                        int h_ = col >> 7, d = col & (HD - 1);
                        Ob[((size_t)(b_ * NH + h_) * S_LEN + s) * HD + d] = f2bf(val);
                    } else {
                        Of[(size_t)mrow * HIDDEN + col] = val;
                    }
                }
            }
    }
}

// ---------------------------------------------------------------------------
__global__ void rope_table_k(float* tab)
{
    int i = blockIdx.x * 256 + threadIdx.x;
    if (i >= S_LEN * 64) return;
    int s = i >> 6, d = i & 63;
    float inv = 1.0f / powf(10000.0f, (float)d * (1.0f / 64.0f));
    float ang = (float)s * inv;
    tab[2 * i]     = cosf(ang);
    tab[2 * i + 1] = sinf(ang);
}

__global__ void rope_apply_k(short* Q, short* K, const float* tab)
{
    int i = blockIdx.x * 256 + threadIdx.x;
    int d8 = i & 7;
    int s  = (i >> 3) & (S_LEN - 1);
    int bh = i >> 14;
    size_t base = ((size_t)bh * S_LEN + s) * HD + d8 * 8;
    const float* tp = tab + (s * 64 + d8 * 8) * 2;
    f32x4 t[4];
#pragma unroll
    for (int j = 0; j < 4; ++j) t[j] = *(const f32x4*)(tp + j * 4);

    bf16x8 q1 = *(bf16x8*)(Q + base), q2 = *(bf16x8*)(Q + base + 64);
    bf16x8 k1 = *(bf16x8*)(K + base), k2 = *(bf16x8*)(K + base + 64);
    short oq1[8], oq2[8], ok1[8], ok2[8];
    const float qs = 0.08838834764831845f;
#pragma unroll
    for (int j = 0; j < 8; ++j) {
        float c  = t[j >> 1][(j & 1) * 2];
        float sn = t[j >> 1][(j & 1) * 2 + 1];
        float a1 = bf2f(q1[j]), a2 = bf2f(q2[j]);
        oq1[j] = f2bf((a1 * c - a2 * sn) * qs);
        oq2[j] = f2bf((a2 * c + a1 * sn) * qs);
        float b1 = bf2f(k1[j]), b2 = bf2f(k2[j]);
        ok1[j] = f2bf(b1 * c - b2 * sn);
        ok2[j] = f2bf(b2 * c + b1 * sn);
    }
    *(bf16x8*)(Q + base)      = *(bf16x8*)oq1;
    *(bf16x8*)(Q + base + 64) = *(bf16x8*)oq2;
    *(bf16x8*)(K + base)      = *(bf16x8*)ok1;
    *(bf16x8*)(K + base + 64) = *(bf16x8*)ok2;
}

// ---------------------------------------------------------------------------
// Causal flash attention (unchanged from round 6).
// ---------------------------------------------------------------------------
__global__ __launch_bounds__(256, 2)
void attn_k(const short* Q, const short* K, const short* Vt, short* AO)
{
    __shared__ short Ks[2][64 * 128];   // 32 KB
    __shared__ short Vs[2][128 * 64];   // 32 KB

    const int tid = threadIdx.x, lane = tid & 63, wv = tid >> 6;
    const int fr = lane & 15, fg = lane >> 4;
    const int bid = blockIdx.x;
    const int bh   = bid & 31;
    const int sub  = bid >> 5;          // 0..15
    const int p    = sub >> 1;          // 0..7
    const int half = sub & 1;

    const short* Qb = Q  + (size_t)bh * S_LEN * HD;
    const short* Kb = K  + (size_t)bh * S_LEN * HD;
    const short* Vb = Vt + (size_t)bh * HD * S_LEN;
    const int b_ = bh >> 4, h = bh & 15;

#define SWK(r) (((r) & 3) | ((((r) >> 3) & 3) << 2))
#define STAGE(t, bufi)                                                          \
    do {                                                                        \
        const int kb_ = (t) * 64;                                               \
        _Pragma("unroll")                                                       \
        for (int i_ = 0; i_ < 4; ++i_) {                                        \
            int c_ = i_ * 256 + tid;                                            \
            int r_ = c_ >> 4, bb_ = c_ & 15;                                    \
            gload16(Kb + (size_t)(kb_ + r_) * HD + ((bb_ ^ SWK(r_)) * 8),       \
                    (char*)&Ks[bufi][0] + (i_ * 256 + wv * 64) * 16);           \
        }                                                                       \
        _Pragma("unroll")                                                       \
        for (int i_ = 0; i_ < 4; ++i_) {                                        \
            int c_ = i_ * 256 + tid;                                            \
            int r_ = c_ >> 3, bb_ = c_ & 7;                                     \
            gload16(Vb + (size_t)r_ * S_LEN + kb_ + ((bb_ ^ (r_ & 7)) * 8),     \
                    (char*)&Vs[bufi][0] + (i_ * 256 + wv * 64) * 16);           \
        }                                                                       \
    } while (0)

#pragma unroll 1
    for (int phase = 0; phase < 2; ++phase) {
        const int qt = phase ? (15 - p) : p;
        const int qbase = qt * 128 + half * 64 + wv * 16;

        bf16x8 qf[4];
#pragma unroll
        for (int ks = 0; ks < 4; ++ks)
            qf[ks] = *(const bf16x8*)(Qb + (size_t)(qbase + fr) * HD
                                      + ks * 32 + fg * 8);

        f32x4 oT[8];
#pragma unroll
        for (int nd = 0; nd < 8; ++nd) oT[nd] = (f32x4){0.f, 0.f, 0.f, 0.f};
        float mrun = -1e30f, lrun = 0.f;

        const int ntiles = qt * 2 + 1 + half;
        __syncthreads();                 // prev phase's LDS reads done
        STAGE(0, 0);

        for (int t = 0; t < ntiles; ++t) {
            const int buf = t & 1;
            __syncthreads();             // drains vmcnt -> buf ready
            if (t + 1 < ntiles) STAGE(t + 1, buf ^ 1);
            const int kb = t * 64;

            if (kb <= qbase + 15) {      // wave-uniform causal skip
                f32x4 sc[4];
#pragma unroll
                for (int ni = 0; ni < 4; ++ni) sc[ni] = (f32x4){0.f, 0.f, 0.f, 0.f};
                __builtin_amdgcn_s_setprio(1);
#pragma unroll
                for (int ks = 0; ks < 4; ++ks) {
                    bf16x8 kf[4];
#pragma unroll
                    for (int ni = 0; ni < 4; ++ni) {
                        int rk = ((ni & 1) << 5) + ((fr >> 2) << 3)
                               + ((ni >> 1) << 2) + (fr & 3);
                        kf[ni] = *(const bf16x8*)&Ks[buf][rk * 128
                                     + (((ks * 4 + fg) ^ fr) * 8)];
                    }
#pragma unroll
                    for (int ni = 0; ni < 4; ++ni)
                        sc[ni] = mfma16(kf[ni], qf[ks], sc[ni]);
                }
                __builtin_amdgcn_s_setprio(0);
                const int qrow = qbase + fr;
                if (kb + 63 > qbase) {   // masking tile
#pragma unroll
                    for (int ni = 0; ni < 4; ++ni)
#pragma unroll
                        for (int j = 0; j < 4; ++j) {
                            int kcol = kb + ((ni & 1) << 5) + (fg << 3)
                                     + ((ni >> 1) << 2) + j;
                            if (kcol > qrow) sc[ni][j] = -1e30f;
                        }
                }
                float mx = sc[0][0];
#pragma unroll
                for (int ni = 0; ni < 4; ++ni)
#pragma unroll
                    for (int j = 0; j < 4; ++j) mx = fmaxf(mx, sc[ni][j]);
                mx = fmaxf(mx, __shfl_xor(mx, 16));
                mx = fmaxf(mx, __shfl_xor(mx, 32));
                if (mx > mrun) {
                    float scale = __expf(mrun - mx);
                    mrun = mx;
                    lrun *= scale;
#pragma unroll
                    for (int nd = 0; nd < 8; ++nd)
#pragma unroll
                        for (int j = 0; j < 4; ++j) oT[nd][j] *= scale;
                }
                float rs = 0.f;
                short pw[16];
#pragma unroll
                for (int ni = 0; ni < 4; ++ni)
#pragma unroll
                    for (int j = 0; j < 4; ++j) {
                        float pe = __expf(sc[ni][j] - mrun);
                        rs += pe;
                        pw[((ni & 1) << 3) + ((ni >> 1) << 2) + j] = f2bf(pe);
                    }
                bf16x8 pf0 = *(bf16x8*)&pw[0];
                bf16x8 pf1 = *(bf16x8*)&pw[8];
                rs += __shfl_xor(rs, 16);
                rs += __shfl_xor(rs, 32);
                lrun += rs;
                __builtin_amdgcn_s_setprio(1);
#pragma unroll
                for (int nd = 0; nd < 8; ++nd) {
                    const int d = nd * 16 + fr;
                    bf16x8 vf0 = *(const bf16x8*)&Vs[buf][d * 64 + ((fg ^ (d & 7)) * 8)];
                    bf16x8 vf1 = *(const bf16x8*)&Vs[buf][d * 64 + (((4 + fg) ^ (d & 7)) * 8)];
                    oT[nd] = mfma16(vf0, pf0, oT[nd]);
                    oT[nd] = mfma16(vf1, pf1, oT[nd]);
                }
                __builtin_amdgcn_s_setprio(0);
            }
        }

        float inv = 1.0f / lrun;
        int srow = qbase + fr;
#pragma unroll
        for (int nd = 0; nd < 8; ++nd) {
            s16x4 w;
#pragma unroll
            for (int j = 0; j < 4; ++j) w[j] = f2bf(oT[nd][j] * inv);
            *(s16x4*)(AO + ((size_t)b_ * S_LEN + srow) * HIDDEN
                      + h * HD + nd * 16 + fg * 4) = w;
        }
    }
#undef STAGE
#undef SWK
}

// ---------------------------------------------------------------------------
extern "C" void kernel_launch(void* const* d_in, const int* in_sizes, int n_in,
                              void* d_out, int out_size, void* d_ws, size_t ws_size,
                              hipStream_t stream)
{
    const float* hs = (const float*)d_in[0];
    const float* wq = (const float*)d_in[1];
    const float* wk = (const float*)d_in[2];
    const float* wvp = (const float*)d_in[3];
    const float* wo = (const float*)d_in[4];
    float* out = (float*)d_out;

    char* ws = (char*)d_ws;
    short* CB  = (short*)ws;
    short* Hb  = CB;
    short* Wqb = CB + 2 * (size_t)SEG;
    short* Wkb = CB + 3 * (size_t)SEG;
    short* Wvb = CB + 4 * (size_t)SEG;
    short* Wob = CB + 5 * (size_t)SEG;
    short* Qb  = (short*)(ws + 50331648);
    short* Kb  = (short*)(ws + 67108864);
    short* Vb  = (short*)(ws + 83886080);   // [bh][d][s]
    short* AO  = Hb;                         // alias: hidden dead after gemm<0>
    float* tab = (float*)(ws + 100663296);

    cast_k<<<dim3(12288), dim3(256), 0, stream>>>(hs, wq, wk, wvp, wo, CB);
    rope_table_k<<<dim3(512), dim3(256), 0, stream>>>(tab);
    gemm8p<0><<<dim3(16, 48), dim3(512), 0, stream>>>(
        Hb, Wqb, Wkb, Wvb, Qb, Kb, Vb, nullptr);
    rope_apply_k<<<dim3(2048), dim3(256), 0, stream>>>(Qb, Kb, tab);
    attn_k<<<dim3(512), dim3(256), 0, stream>>>(Qb, Kb, Vb, AO);
    gemm8p<1><<<dim3(16, 16), dim3(512), 0, stream>>>(
        AO, Wob, nullptr, nullptr, nullptr, nullptr, nullptr, out);
}

// Round 8
// 359.268 us; speedup vs baseline: 1.0203x; 1.0203x over previous
//
#include <hip/hip_runtime.h>
#include <hip/hip_bf16.h>

#define S_LEN  2048
#define BATCH  2
#define NH     16
#define HD     128
#define HIDDEN 2048
#define MROWS  (BATCH*S_LEN)   // 4096

typedef __attribute__((ext_vector_type(8))) short bf16x8;
typedef __attribute__((ext_vector_type(4))) short s16x4;
typedef __attribute__((ext_vector_type(4))) float f32x4;

__device__ __forceinline__ float bf2f(short s) {
    union { float f; unsigned int u; } v;
    v.u = ((unsigned int)(unsigned short)s) << 16;
    return v.f;
}
__device__ __forceinline__ short f2bf(float f) {
    union { float f; unsigned int u; } v;
    v.f = f;
    unsigned int r = v.u + 0x7fffu + ((v.u >> 16) & 1u);   // RNE, inputs never NaN
    return (short)(r >> 16);
}
__device__ __forceinline__ f32x4 mfma16(bf16x8 a, bf16x8 b, f32x4 c) {
    return __builtin_amdgcn_mfma_f32_16x16x32_bf16(a, b, c, 0, 0, 0);
}
__device__ __forceinline__ void gload16(const void* g, void* l) {
    __builtin_amdgcn_global_load_lds(
        (const __attribute__((address_space(1))) void*)g,
        (__attribute__((address_space(3))) void*)l, 16, 0, 0);
}
#define SBAR()  asm volatile("s_barrier" ::: "memory")
#define LGKM0() do { asm volatile("s_waitcnt lgkmcnt(0)" ::: "memory"); \
                     __builtin_amdgcn_sched_barrier(0); } while (0)

// ---------------------------------------------------------------------------
// Cast fp32 -> bf16: hidden (2 x 4M segs), wq, wk, wv, wo (1 seg each).
// ---------------------------------------------------------------------------
#define SEG (4194304)
__global__ void cast_k(const float* hs, const float* wq, const float* wk,
                       const float* wv, const float* wo, short* dst)
{
    size_t i = ((size_t)blockIdx.x * 256 + threadIdx.x) * 8;
    int seg = (int)(i >> 22);
    const float* s;
    size_t off;
    if (seg < 2)      { s = hs; off = i; }
    else if (seg == 2){ s = wq; off = i - 2 * (size_t)SEG; }
    else if (seg == 3){ s = wk; off = i - 3 * (size_t)SEG; }
    else if (seg == 4){ s = wv; off = i - 4 * (size_t)SEG; }
    else              { s = wo; off = i - 5 * (size_t)SEG; }
    f32x4 lo = *(const f32x4*)(s + off);
    f32x4 hi = *(const f32x4*)(s + off + 4);
    short v[8];
#pragma unroll
    for (int j = 0; j < 4; ++j) { v[j] = f2bf(lo[j]); v[4 + j] = f2bf(hi[j]); }
    *(bf16x8*)(dst + i) = *(bf16x8*)v;
}

// ---------------------------------------------------------------------------
// 8-wave pipelined GEMM: C[M][N] = A[M][K] * W[N][K]^T, bf16.
// BM=256, BN=128, BK=64. 3-deep K-tile LDS slots (144 KB), stage t+2 while
// computing t. 2 phases/tile x {8 ds_read_b128, 16 MFMA}; vmcnt(6) once per
// tile (never 0 in steady state); raw s_barrier; setprio around MFMA.
// LDS row layout (proven): row*64 shorts, 16B chunk kc stored at (kc^(r&7)).
// MODE 0: W in {wq,wk,wv}; C bf16 -> Q/K [bh][s][d], V transposed [bh][d][s]
// MODE 1: W = wo; C fp32 [M][N]
// ---------------------------------------------------------------------------
template<int MODE>
__global__ __launch_bounds__(512, 1)
void gemm8p(const short* A, const short* W0, const short* W1, const short* W2,
            short* Oq, short* Ok, short* Ov, float* Of)
{
    __shared__ short lds[73728];   // 144 KB: slot s @ s*48KB: A 32KB + B 16KB

    const int tid  = threadIdx.x;
    const int lane = tid & 63;
    const int wv   = tid >> 6;          // 0..7
    const int wr   = wv & 3, wc = wv >> 2;
    const int fr   = lane & 15, fg = lane >> 4;

    const int mt = blockIdx.x;
    int nt = blockIdx.y;
    const short* W = W0;
    short* Ob = Oq;
    int osel = 0;
    if (MODE == 0) {
        osel = nt >> 4; nt &= 15;
        W  = (osel == 0) ? W0 : (osel == 1) ? W1 : W2;
        Ob = (osel == 0) ? Oq : (osel == 1) ? Ok : Ov;
    }
    const int row0 = mt * 256, col0 = nt * 128;

    // stage one full K-tile (64-wide) into slot sl: 4 A-loads + 2 B-loads/thread
#define STAGET(t_, sl_)                                                         \
    do {                                                                        \
        const int kg_ = (t_) * 64;                                              \
        _Pragma("unroll")                                                       \
        for (int it_ = 0; it_ < 4; ++it_) {                                     \
            int c_ = it_ * 512 + tid;                                           \
            int r_ = c_ >> 3;                                                   \
            gload16(A + (size_t)(row0 + r_) * HIDDEN + kg_                      \
                        + (((c_ & 7) ^ (r_ & 7)) * 8),                          \
                    (char*)lds + (sl_) * 49152 + c_ * 16);                      \
        }                                                                       \
        _Pragma("unroll")                                                       \
        for (int it_ = 0; it_ < 2; ++it_) {                                     \
            int c_ = it_ * 512 + tid;                                           \
            int r_ = c_ >> 3;                                                   \
            gload16(W + (size_t)(col0 + r_) * HIDDEN + kg_                      \
                        + (((c_ & 7) ^ (r_ & 7)) * 8),                          \
                    (char*)lds + (sl_) * 49152 + 32768 + c_ * 16);              \
        }                                                                       \
    } while (0)

    auto ldsA = [&](int sl, int r, int kc) -> bf16x8 {
        return *(const bf16x8*)((const char*)lds + sl * 49152
                                + r * 128 + ((kc ^ (r & 7)) * 16));
    };
    auto ldsB = [&](int sl, int r, int kc) -> bf16x8 {
        return *(const bf16x8*)((const char*)lds + sl * 49152 + 32768
                                + r * 128 + ((kc ^ (r & 7)) * 16));
    };

    f32x4 acc[4][4];
#pragma unroll
    for (int m = 0; m < 4; ++m)
#pragma unroll
        for (int n = 0; n < 4; ++n) acc[m][n] = (f32x4){0.f, 0.f, 0.f, 0.f};

    const int NT = HIDDEN / 64;          // 32 K-tiles
    // prologue: stage tiles 0,1 (12 loads); wait tile 0 (6 left in flight)
    STAGET(0, 0);
    STAGET(1, 1);
    asm volatile("s_waitcnt vmcnt(6)" ::: "memory");
    SBAR();

#pragma unroll 1
    for (int t = 0; t < NT; ++t) {
        const int sl = t % 3;
        // ---- phase 0: ks=0 reads; stage tile t+2; 16 MFMA ----
        bf16x8 a0 = ldsA(sl, wr * 64 +  0 + fr, fg);
        bf16x8 a1 = ldsA(sl, wr * 64 + 16 + fr, fg);
        bf16x8 a2 = ldsA(sl, wr * 64 + 32 + fr, fg);
        bf16x8 a3 = ldsA(sl, wr * 64 + 48 + fr, fg);
        bf16x8 b0 = ldsB(sl, wc * 64 +  0 + fr, fg);
        bf16x8 b1 = ldsB(sl, wc * 64 + 16 + fr, fg);
        bf16x8 b2 = ldsB(sl, wc * 64 + 32 + fr, fg);
        bf16x8 b3 = ldsB(sl, wc * 64 + 48 + fr, fg);
        if (t + 2 < NT) STAGET(t + 2, (t + 2) % 3);
        SBAR();
        LGKM0();
        __builtin_amdgcn_s_setprio(1);
        acc[0][0] = mfma16(a0, b0, acc[0][0]);
        acc[0][1] = mfma16(a0, b1, acc[0][1]);
        acc[0][2] = mfma16(a0, b2, acc[0][2]);
        acc[0][3] = mfma16(a0, b3, acc[0][3]);
        acc[1][0] = mfma16(a1, b0, acc[1][0]);
        acc[1][1] = mfma16(a1, b1, acc[1][1]);
        acc[1][2] = mfma16(a1, b2, acc[1][2]);
        acc[1][3] = mfma16(a1, b3, acc[1][3]);
        acc[2][0] = mfma16(a2, b0, acc[2][0]);
        acc[2][1] = mfma16(a2, b1, acc[2][1]);
        acc[2][2] = mfma16(a2, b2, acc[2][2]);
        acc[2][3] = mfma16(a2, b3, acc[2][3]);
        acc[3][0] = mfma16(a3, b0, acc[3][0]);
        acc[3][1] = mfma16(a3, b1, acc[3][1]);
        acc[3][2] = mfma16(a3, b2, acc[3][2]);
        acc[3][3] = mfma16(a3, b3, acc[3][3]);
        __builtin_amdgcn_s_setprio(0);
        SBAR();
        // ---- phase 1: ks=1 reads; 16 MFMA; counted vmcnt at tile boundary --
        a0 = ldsA(sl, wr * 64 +  0 + fr, 4 + fg);
        a1 = ldsA(sl, wr * 64 + 16 + fr, 4 + fg);
        a2 = ldsA(sl, wr * 64 + 32 + fr, 4 + fg);
        a3 = ldsA(sl, wr * 64 + 48 + fr, 4 + fg);
        b0 = ldsB(sl, wc * 64 +  0 + fr, 4 + fg);
        b1 = ldsB(sl, wc * 64 + 16 + fr, 4 + fg);
        b2 = ldsB(sl, wc * 64 + 32 + fr, 4 + fg);
        b3 = ldsB(sl, wc * 64 + 48 + fr, 4 + fg);
        SBAR();
        LGKM0();
        __builtin_amdgcn_s_setprio(1);
        acc[0][0] = mfma16(a0, b0, acc[0][0]);
        acc[0][1] = mfma16(a0, b1, acc[0][1]);
        acc[0][2] = mfma16(a0, b2, acc[0][2]);
        acc[0][3] = mfma16(a0, b3, acc[0][3]);
        acc[1][0] = mfma16(a1, b0, acc[1][0]);
        acc[1][1] = mfma16(a1, b1, acc[1][1]);
        acc[1][2] = mfma16(a1, b2, acc[1][2]);
        acc[1][3] = mfma16(a1, b3, acc[1][3]);
        acc[2][0] = mfma16(a2, b0, acc[2][0]);
        acc[2][1] = mfma16(a2, b1, acc[2][1]);
        acc[2][2] = mfma16(a2, b2, acc[2][2]);
        acc[2][3] = mfma16(a2, b3, acc[2][3]);
        acc[3][0] = mfma16(a3, b0, acc[3][0]);
        acc[3][1] = mfma16(a3, b1, acc[3][1]);
        acc[3][2] = mfma16(a3, b2, acc[3][2]);
        acc[3][3] = mfma16(a3, b3, acc[3][3]);
        __builtin_amdgcn_s_setprio(0);
        if (t + 2 < NT) asm volatile("s_waitcnt vmcnt(6)" ::: "memory");
        else            asm volatile("s_waitcnt vmcnt(0)" ::: "memory");
        SBAR();
    }
#undef STAGET

    // ---- epilogue ----
    if (MODE == 0 && osel == 2) {
        // V: transpose 256x128 tile through LDS, store [bh][d][s] coalesced
        __syncthreads();
#pragma unroll
        for (int m = 0; m < 4; ++m)
#pragma unroll
            for (int j = 0; j < 4; ++j) {
                int row = wr * 64 + m * 16 + fg * 4 + j;   // s in tile (0..255)
#pragma unroll
                for (int n = 0; n < 4; ++n) {
                    int col = wc * 64 + n * 16 + fr;       // d (0..127)
                    lds[col * 256 + (((row >> 3) ^ (col & 31)) * 8) + (row & 7)] =
                        f2bf(acc[m][n][j]);
                }
            }
        __syncthreads();
        const int b_ = row0 >> 11;
        const int bh = b_ * NH + nt;
        const int s0 = row0 & (S_LEN - 1);
#pragma unroll
        for (int it = 0; it < 8; ++it) {
            int c = it * 512 + tid;                 // 0..4095
            int d = c >> 5, sc = c & 31;
            bf16x8 vv = *(const bf16x8*)&lds[d * 256 + ((sc ^ (d & 31)) * 8)];
            *(bf16x8*)(Ov + ((size_t)bh * HD + d) * S_LEN + s0 + sc * 8) = vv;
        }
    } else {
#pragma unroll
        for (int m = 0; m < 4; ++m)
#pragma unroll
            for (int j = 0; j < 4; ++j) {
                int mrow = row0 + wr * 64 + m * 16 + fg * 4 + j;
#pragma unroll
                for (int n = 0; n < 4; ++n) {
                    int col = col0 + wc * 64 + n * 16 + fr;
                    float val = acc[m][n][j];
                    if (MODE == 0) {
                        int b_ = mrow >> 11, s = mrow & (S_LEN - 1);
                        int h_ = col >> 7, d = col & (HD - 1);
                        Ob[((size_t)(b_ * NH + h_) * S_LEN + s) * HD + d] = f2bf(val);
                    } else {
                        Of[(size_t)mrow * HIDDEN + col] = val;
                    }
                }
            }
    }
}

// ---------------------------------------------------------------------------
__global__ void rope_table_k(float* tab)
{
    int i = blockIdx.x * 256 + threadIdx.x;
    if (i >= S_LEN * 64) return;
    int s = i >> 6, d = i & 63;
    float inv = 1.0f / powf(10000.0f, (float)d * (1.0f / 64.0f));
    float ang = (float)s * inv;
    tab[2 * i]     = cosf(ang);
    tab[2 * i + 1] = sinf(ang);
}

__global__ void rope_apply_k(short* Q, short* K, const float* tab)
{
    int i = blockIdx.x * 256 + threadIdx.x;
    int d8 = i & 7;
    int s  = (i >> 3) & (S_LEN - 1);
    int bh = i >> 14;
    size_t base = ((size_t)bh * S_LEN + s) * HD + d8 * 8;
    const float* tp = tab + (s * 64 + d8 * 8) * 2;
    f32x4 t[4];
#pragma unroll
    for (int j = 0; j < 4; ++j) t[j] = *(const f32x4*)(tp + j * 4);

    bf16x8 q1 = *(bf16x8*)(Q + base), q2 = *(bf16x8*)(Q + base + 64);
    bf16x8 k1 = *(bf16x8*)(K + base), k2 = *(bf16x8*)(K + base + 64);
    short oq1[8], oq2[8], ok1[8], ok2[8];
    const float qs = 0.08838834764831845f;
#pragma unroll
    for (int j = 0; j < 8; ++j) {
        float c  = t[j >> 1][(j & 1) * 2];
        float sn = t[j >> 1][(j & 1) * 2 + 1];
        float a1 = bf2f(q1[j]), a2 = bf2f(q2[j]);
        oq1[j] = f2bf((a1 * c - a2 * sn) * qs);
        oq2[j] = f2bf((a2 * c + a1 * sn) * qs);
        float b1 = bf2f(k1[j]), b2 = bf2f(k2[j]);
        ok1[j] = f2bf(b1 * c - b2 * sn);
        ok2[j] = f2bf(b2 * c + b1 * sn);
    }
    *(bf16x8*)(Q + base)      = *(bf16x8*)oq1;
    *(bf16x8*)(Q + base + 64) = *(bf16x8*)oq2;
    *(bf16x8*)(K + base)      = *(bf16x8*)ok1;
    *(bf16x8*)(K + base + 64) = *(bf16x8*)ok2;
}

// ---------------------------------------------------------------------------
// Causal flash attention (unchanged).
// ---------------------------------------------------------------------------
__global__ __launch_bounds__(256, 2)
void attn_k(const short* Q, const short* K, const short* Vt, short* AO)
{
    __shared__ short Ks[2][64 * 128];   // 32 KB
    __shared__ short Vs[2][128 * 64];   // 32 KB

    const int tid = threadIdx.x, lane = tid & 63, wv = tid >> 6;
    const int fr = lane & 15, fg = lane >> 4;
    const int bid = blockIdx.x;
    const int bh   = bid & 31;
    const int sub  = bid >> 5;          // 0..15
    const int p    = sub >> 1;          // 0..7
    const int half = sub & 1;

    const short* Qb = Q  + (size_t)bh * S_LEN * HD;
    const short* Kb = K  + (size_t)bh * S_LEN * HD;
    const short* Vb = Vt + (size_t)bh * HD * S_LEN;
    const int b_ = bh >> 4, h = bh & 15;

#define SWK(r) (((r) & 3) | ((((r) >> 3) & 3) << 2))
#define STAGE(t, bufi)                                                          \
    do {                                                                        \
        const int kb_ = (t) * 64;                                               \
        _Pragma("unroll")                                                       \
        for (int i_ = 0; i_ < 4; ++i_) {                                        \
            int c_ = i_ * 256 + tid;                                            \
            int r_ = c_ >> 4, bb_ = c_ & 15;                                    \
            gload16(Kb + (size_t)(kb_ + r_) * HD + ((bb_ ^ SWK(r_)) * 8),       \
                    (char*)&Ks[bufi][0] + (i_ * 256 + wv * 64) * 16);           \
        }                                                                       \
        _Pragma("unroll")                                                       \
        for (int i_ = 0; i_ < 4; ++i_) {                                        \
            int c_ = i_ * 256 + tid;                                            \
            int r_ = c_ >> 3, bb_ = c_ & 7;                                     \
            gload16(Vb + (size_t)r_ * S_LEN + kb_ + ((bb_ ^ (r_ & 7)) * 8),     \
                    (char*)&Vs[bufi][0] + (i_ * 256 + wv * 64) * 16);           \
        }                                                                       \
    } while (0)

#pragma unroll 1
    for (int phase = 0; phase < 2; ++phase) {
        const int qt = phase ? (15 - p) : p;
        const int qbase = qt * 128 + half * 64 + wv * 16;

        bf16x8 qf[4];
#pragma unroll
        for (int ks = 0; ks < 4; ++ks)
            qf[ks] = *(const bf16x8*)(Qb + (size_t)(qbase + fr) * HD
                                      + ks * 32 + fg * 8);

        f32x4 oT[8];
#pragma unroll
        for (int nd = 0; nd < 8; ++nd) oT[nd] = (f32x4){0.f, 0.f, 0.f, 0.f};
        float mrun = -1e30f, lrun = 0.f;

        const int ntiles = qt * 2 + 1 + half;
        __syncthreads();                 // prev phase's LDS reads done
        STAGE(0, 0);

        for (int t = 0; t < ntiles; ++t) {
            const int buf = t & 1;
            __syncthreads();             // drains vmcnt -> buf ready
            if (t + 1 < ntiles) STAGE(t + 1, buf ^ 1);
            const int kb = t * 64;

            if (kb <= qbase + 15) {      // wave-uniform causal skip
                f32x4 sc[4];
#pragma unroll
                for (int ni = 0; ni < 4; ++ni) sc[ni] = (f32x4){0.f, 0.f, 0.f, 0.f};
                __builtin_amdgcn_s_setprio(1);
#pragma unroll
                for (int ks = 0; ks < 4; ++ks) {
                    bf16x8 kf[4];
#pragma unroll
                    for (int ni = 0; ni < 4; ++ni) {
                        int rk = ((ni & 1) << 5) + ((fr >> 2) << 3)
                               + ((ni >> 1) << 2) + (fr & 3);
                        kf[ni] = *(const bf16x8*)&Ks[buf][rk * 128
                                     + (((ks * 4 + fg) ^ fr) * 8)];
                    }
#pragma unroll
                    for (int ni = 0; ni < 4; ++ni)
                        sc[ni] = mfma16(kf[ni], qf[ks], sc[ni]);
                }
                __builtin_amdgcn_s_setprio(0);
                const int qrow = qbase + fr;
                if (kb + 63 > qbase) {   // masking tile
#pragma unroll
                    for (int ni = 0; ni < 4; ++ni)
#pragma unroll
                        for (int j = 0; j < 4; ++j) {
                            int kcol = kb + ((ni & 1) << 5) + (fg << 3)
                                     + ((ni >> 1) << 2) + j;
                            if (kcol > qrow) sc[ni][j] = -1e30f;
                        }
                }
                float mx = sc[0][0];
#pragma unroll
                for (int ni = 0; ni < 4; ++ni)
#pragma unroll
                    for (int j = 0; j < 4; ++j) mx = fmaxf(mx, sc[ni][j]);
                mx = fmaxf(mx, __shfl_xor(mx, 16));
                mx = fmaxf(mx, __shfl_xor(mx, 32));
                if (mx > mrun) {
                    float scale = __expf(mrun - mx);
                    mrun = mx;
                    lrun *= scale;
#pragma unroll
                    for (int nd = 0; nd < 8; ++nd)
#pragma unroll
                        for (int j = 0; j < 4; ++j) oT[nd][j] *= scale;
                }
                float rs = 0.f;
                short pw[16];
#pragma unroll
                for (int ni = 0; ni < 4; ++ni)
#pragma unroll
                    for (int j = 0; j < 4; ++j) {
                        float pe = __expf(sc[ni][j] - mrun);
                        rs += pe;
                        pw[((ni & 1) << 3) + ((ni >> 1) << 2) + j] = f2bf(pe);
                    }
                bf16x8 pf0 = *(bf16x8*)&pw[0];
                bf16x8 pf1 = *(bf16x8*)&pw[8];
                rs += __shfl_xor(rs, 16);
                rs += __shfl_xor(rs, 32);
                lrun += rs;
                __builtin_amdgcn_s_setprio(1);
#pragma unroll
                for (int nd = 0; nd < 8; ++nd) {
                    const int d = nd * 16 + fr;
                    bf16x8 vf0 = *(const bf16x8*)&Vs[buf][d * 64 + ((fg ^ (d & 7)) * 8)];
                    bf16x8 vf1 = *(const bf16x8*)&Vs[buf][d * 64 + (((4 + fg) ^ (d & 7)) * 8)];
                    oT[nd] = mfma16(vf0, pf0, oT[nd]);
                    oT[nd] = mfma16(vf1, pf1, oT[nd]);
                }
                __builtin_amdgcn_s_setprio(0);
            }
        }

        float inv = 1.0f / lrun;
        int srow = qbase + fr;
#pragma unroll
        for (int nd = 0; nd < 8; ++nd) {
            s16x4 w;
#pragma unroll
            for (int j = 0; j < 4; ++j) w[j] = f2bf(oT[nd][j] * inv);
            *(s16x4*)(AO + ((size_t)b_ * S_LEN + srow) * HIDDEN
                      + h * HD + nd * 16 + fg * 4) = w;
        }
    }
#undef STAGE
#undef SWK
}

// ---------------------------------------------------------------------------
extern "C" void kernel_launch(void* const* d_in, const int* in_sizes, int n_in,
                              void* d_out, int out_size, void* d_ws, size_t ws_size,
                              hipStream_t stream)
{
    const float* hs = (const float*)d_in[0];
    const float* wq = (const float*)d_in[1];
    const float* wk = (const float*)d_in[2];
    const float* wvp = (const float*)d_in[3];
    const float* wo = (const float*)d_in[4];
    float* out = (float*)d_out;

    char* ws = (char*)d_ws;
    short* CB  = (short*)ws;
    short* Hb  = CB;
    short* Wqb = CB + 2 * (size_t)SEG;
    short* Wkb = CB + 3 * (size_t)SEG;
    short* Wvb = CB + 4 * (size_t)SEG;
    short* Wob = CB + 5 * (size_t)SEG;
    short* Qb  = (short*)(ws + 50331648);
    short* Kb  = (short*)(ws + 67108864);
    short* Vb  = (short*)(ws + 83886080);   // [bh][d][s]
    short* AO  = Hb;                         // alias: hidden dead after gemm<0>
    float* tab = (float*)(ws + 100663296);

    cast_k<<<dim3(12288), dim3(256), 0, stream>>>(hs, wq, wk, wvp, wo, CB);
    rope_table_k<<<dim3(512), dim3(256), 0, stream>>>(tab);
    gemm8p<0><<<dim3(16, 48), dim3(512), 0, stream>>>(
        Hb, Wqb, Wkb, Wvb, Qb, Kb, Vb, nullptr);
    rope_apply_k<<<dim3(2048), dim3(256), 0, stream>>>(Qb, Kb, tab);
    attn_k<<<dim3(512), dim3(256), 0, stream>>>(Qb, Kb, Vb, AO);
    gemm8p<1><<<dim3(16, 16), dim3(512), 0, stream>>>(
        AO, Wob, nullptr, nullptr, nullptr, nullptr, nullptr, out);
}

// Round 11
// 343.792 us; speedup vs baseline: 1.0662x; 1.0450x over previous
//
#include <hip/hip_runtime.h>
#include <hip/hip_bf16.h>

#define S_LEN  2048
#define BATCH  2
#define NH     16
#define HD     128
#define HIDDEN 2048
#define MROWS  (BATCH*S_LEN)   // 4096

typedef __attribute__((ext_vector_type(8))) short bf16x8;
typedef __attribute__((ext_vector_type(4))) short s16x4;
typedef __attribute__((ext_vector_type(4))) float f32x4;

__device__ __forceinline__ float bf2f(short s) {
    union { float f; unsigned int u; } v;
    v.u = ((unsigned int)(unsigned short)s) << 16;
    return v.f;
}
__device__ __forceinline__ short f2bf(float f) {
    union { float f; unsigned int u; } v;
    v.f = f;
    unsigned int r = v.u + 0x7fffu + ((v.u >> 16) & 1u);   // RNE, inputs never NaN
    return (short)(r >> 16);
}
__device__ __forceinline__ f32x4 mfma16(bf16x8 a, bf16x8 b, f32x4 c) {
    return __builtin_amdgcn_mfma_f32_16x16x32_bf16(a, b, c, 0, 0, 0);
}
__device__ __forceinline__ void gload16(const void* g, void* l) {
    __builtin_amdgcn_global_load_lds(
        (const __attribute__((address_space(1))) void*)g,
        (__attribute__((address_space(3))) void*)l, 16, 0, 0);
}

// ---------------------------------------------------------------------------
// Cast fp32 -> bf16: hidden (2 x 4M segs), wq, wk, wv, wo (1 seg each).
// ---------------------------------------------------------------------------
#define SEG (4194304)
__global__ void cast_k(const float* hs, const float* wq, const float* wk,
                       const float* wv, const float* wo, short* dst)
{
    size_t i = ((size_t)blockIdx.x * 256 + threadIdx.x) * 8;
    int seg = (int)(i >> 22);
    const float* s;
    size_t off;
    if (seg < 2)      { s = hs; off = i; }
    else if (seg == 2){ s = wq; off = i - 2 * (size_t)SEG; }
    else if (seg == 3){ s = wk; off = i - 3 * (size_t)SEG; }
    else if (seg == 4){ s = wv; off = i - 4 * (size_t)SEG; }
    else              { s = wo; off = i - 5 * (size_t)SEG; }
    f32x4 lo = *(const f32x4*)(s + off);
    f32x4 hi = *(const f32x4*)(s + off + 4);
    short v[8];
#pragma unroll
    for (int j = 0; j < 4; ++j) { v[j] = f2bf(lo[j]); v[4 + j] = f2bf(hi[j]); }
    *(bf16x8*)(dst + i) = *(bf16x8*)v;
}

// ---------------------------------------------------------------------------
// RoPE table: [S][64] pairs (cos, sin)
// ---------------------------------------------------------------------------
__global__ void rope_table_k(float* tab)
{
    int i = blockIdx.x * 256 + threadIdx.x;
    if (i >= S_LEN * 64) return;
    int s = i >> 6, d = i & 63;
    float inv = 1.0f / powf(10000.0f, (float)d * (1.0f / 64.0f));
    float ang = (float)s * inv;
    tab[2 * i]     = cosf(ang);
    tab[2 * i + 1] = sinf(ang);
}

// ---------------------------------------------------------------------------
// GEMM: C[M][N] = A[M][K] * W[N][K]^T, bf16 (m97 structure, proven 1030 TF).
// B-fragment columns remapped to d(n) = (n&1)*64 + (n>>1)*32 + wc*16 + fr so
// each lane holds both halves of every RoPE pair -> RoPE fused lane-locally
// into the MODE-0 epilogue (Q gets 1/sqrt(128) folded in). V transposed.
// MODE 0: W in {wq,wk,wv}; C bf16 -> Q/K [bh][s][d] (RoPE'd), V [bh][d][s]
// MODE 1: W = wo; C fp32 [M][N]
// ---------------------------------------------------------------------------
template<int MODE>
__global__ __launch_bounds__(256, 4)
void gemm_bt(const short* A, const short* W0, const short* W1, const short* W2,
             short* Oq, short* Ok, short* Ov, float* Of, const float* tab)
{
    __shared__ short smem[2 * 128 * 64];
    short* As = smem;
    short* Bs = smem + 128 * 64;

    const int tid  = threadIdx.x;
    const int lane = tid & 63;
    const int wv   = tid >> 6;
    const int wr   = wv >> 1, wc = wv & 1;
    const int fr   = lane & 15, fg = lane >> 4;

    const int mt = blockIdx.x;
    int nt = blockIdx.y;
    const short* W = W0;
    short* Ob = Oq;
    int osel = 0;
    if (MODE == 0) {
        osel = nt >> 4; nt &= 15;
        W  = (osel == 0) ? W0 : (osel == 1) ? W1 : W2;
        Ob = (osel == 0) ? Oq : (osel == 1) ? Ok : Ov;
    }
    const int row0 = mt * 128, col0 = nt * 128;
    const int sr = tid >> 3, sb = tid & 7;

    f32x4 acc[4][4];
#pragma unroll
    for (int m = 0; m < 4; ++m)
#pragma unroll
        for (int n = 0; n < 4; ++n) acc[m][n] = (f32x4){0.f, 0.f, 0.f, 0.f};

    for (int k0 = 0; k0 < HIDDEN; k0 += 64) {
        __syncthreads();
#pragma unroll
        for (int it = 0; it < 4; ++it) {
            int r = it * 32 + sr;
            gload16(A + (size_t)(row0 + r) * HIDDEN + k0 + ((sb ^ (r & 7)) * 8),
                    (char*)As + (it * 256 + wv * 64) * 16);
        }
#pragma unroll
        for (int it = 0; it < 4; ++it) {
            int r = it * 32 + sr;
            gload16(W + (size_t)(col0 + r) * HIDDEN + k0 + ((sb ^ (r & 7)) * 8),
                    (char*)Bs + (it * 256 + wv * 64) * 16);
        }
        __syncthreads();
#pragma unroll
        for (int ks = 0; ks < 2; ++ks) {
            bf16x8 a[4], b[4];
#pragma unroll
            for (int m = 0; m < 4; ++m) {
                int r = wr * 64 + m * 16 + fr;
                a[m] = *(const bf16x8*)&As[r * 64 + (((ks * 4 + fg) ^ (r & 7)) * 8)];
            }
#pragma unroll
            for (int n = 0; n < 4; ++n) {
                int r = ((n & 1) << 6) + ((n >> 1) << 5) + wc * 16 + fr;   // d(n)
                b[n] = *(const bf16x8*)&Bs[r * 64 + (((ks * 4 + fg) ^ (r & 7)) * 8)];
            }
#pragma unroll
            for (int m = 0; m < 4; ++m)
#pragma unroll
                for (int n = 0; n < 4; ++n)
                    acc[m][n] = mfma16(a[m], b[n], acc[m][n]);
        }
    }

    // ---- epilogue ----
    if (MODE == 0 && osel == 2) {
        // V: transpose through LDS, store [bh][d][s] coalesced
        __syncthreads();
#pragma unroll
        for (int m = 0; m < 4; ++m)
#pragma unroll
            for (int j = 0; j < 4; ++j) {
                int row = wr * 64 + m * 16 + fg * 4 + j;   // s within tile
#pragma unroll
                for (int n = 0; n < 4; ++n) {
                    int col = ((n & 1) << 6) + ((n >> 1) << 5) + wc * 16 + fr;
                    smem[col * 128 + (((row >> 3) ^ (col & 15)) * 8) + (row & 7)] =
                        f2bf(acc[m][n][j]);
                }
            }
        __syncthreads();
        const int b_ = row0 >> 11;
        const int bh = b_ * NH + nt;
        const int s0 = row0 & (S_LEN - 1);
#pragma unroll
        for (int it = 0; it < 8; ++it) {
            int c = it * 256 + tid;
            int d = c >> 4, sbk = c & 15;
            bf16x8 vv = *(const bf16x8*)&smem[d * 128 + ((sbk ^ (d & 15)) * 8)];
            *(bf16x8*)(Ov + ((size_t)bh * HD + d) * S_LEN + s0 + sbk * 8) = vv;
        }
    } else if (MODE == 0) {
        // Q/K: fused RoPE (lane-local pairs) + scale for Q
        const float sc_ = (osel == 0) ? 0.08838834764831845f : 1.0f;
        const int d0 = wc * 16 + fr;
#pragma unroll
        for (int m = 0; m < 4; ++m)
#pragma unroll
            for (int j = 0; j < 4; ++j) {
                int mrow = row0 + wr * 64 + m * 16 + fg * 4 + j;
                int s = mrow & (S_LEN - 1), b_ = mrow >> 11;
                const float* t0 = tab + ((s << 6) + d0) * 2;
                const float* t1 = tab + ((s << 6) + 32 + d0) * 2;
                float c0 = t0[0], n0 = t0[1];
                float c1 = t1[0], n1 = t1[1];
                float x0 = acc[m][0][j], y0 = acc[m][1][j];
                float x1 = acc[m][2][j], y1 = acc[m][3][j];
                size_t base = ((size_t)(b_ * NH + nt) * S_LEN + s) * HD;
                Ob[base + d0]      = f2bf((x0 * c0 - y0 * n0) * sc_);
                Ob[base + d0 + 64] = f2bf((y0 * c0 + x0 * n0) * sc_);
                Ob[base + d0 + 32] = f2bf((x1 * c1 - y1 * n1) * sc_);
                Ob[base + d0 + 96] = f2bf((y1 * c1 + x1 * n1) * sc_);
            }
    } else {
#pragma unroll
        for (int m = 0; m < 4; ++m)
#pragma unroll
            for (int j = 0; j < 4; ++j) {
                int mrow = row0 + wr * 64 + m * 16 + fg * 4 + j;
#pragma unroll
                for (int n = 0; n < 4; ++n) {
                    int col = col0 + ((n & 1) << 6) + ((n >> 1) << 5) + wc * 16 + fr;
                    Of[(size_t)mrow * HIDDEN + col] = acc[m][n][j];
                }
            }
    }
}

// ---------------------------------------------------------------------------
// Causal flash attention, swapped-operand, P fully in registers (unchanged).
// ---------------------------------------------------------------------------
__global__ __launch_bounds__(256, 2)
void attn_k(const short* Q, const short* K, const short* Vt, short* AO)
{
    __shared__ short Ks[2][64 * 128];   // 32 KB
    __shared__ short Vs[2][128 * 64];   // 32 KB

    const int tid = threadIdx.x, lane = tid & 63, wv = tid >> 6;
    const int fr = lane & 15, fg = lane >> 4;
    const int bid = blockIdx.x;
    const int bh   = bid & 31;
    const int sub  = bid >> 5;          // 0..15
    const int p    = sub >> 1;          // 0..7
    const int half = sub & 1;

    const short* Qb = Q  + (size_t)bh * S_LEN * HD;
    const short* Kb = K  + (size_t)bh * S_LEN * HD;
    const short* Vb = Vt + (size_t)bh * HD * S_LEN;
    const int b_ = bh >> 4, h = bh & 15;

#define SWK(r) (((r) & 3) | ((((r) >> 3) & 3) << 2))
#define STAGE(t, bufi)                                                          \
    do {                                                                        \
        const int kb_ = (t) * 64;                                               \
        _Pragma("unroll")                                                       \
        for (int i_ = 0; i_ < 4; ++i_) {                                        \
            int c_ = i_ * 256 + tid;                                            \
            int r_ = c_ >> 4, bb_ = c_ & 15;                                    \
            gload16(Kb + (size_t)(kb_ + r_) * HD + ((bb_ ^ SWK(r_)) * 8),       \
                    (char*)&Ks[bufi][0] + (i_ * 256 + wv * 64) * 16);           \
        }                                                                       \
        _Pragma("unroll")                                                       \
        for (int i_ = 0; i_ < 4; ++i_) {                                        \
            int c_ = i_ * 256 + tid;                                            \
            int r_ = c_ >> 3, bb_ = c_ & 7;                                     \
            gload16(Vb + (size_t)r_ * S_LEN + kb_ + ((bb_ ^ (r_ & 7)) * 8),     \
                    (char*)&Vs[bufi][0] + (i_ * 256 + wv * 64) * 16);           \
        }                                                                       \
    } while (0)

#pragma unroll 1
    for (int phase = 0; phase < 2; ++phase) {
        const int qt = phase ? (15 - p) : p;
        const int qbase = qt * 128 + half * 64 + wv * 16;

        bf16x8 qf[4];
#pragma unroll
        for (int ks = 0; ks < 4; ++ks)
            qf[ks] = *(const bf16x8*)(Qb + (size_t)(qbase + fr) * HD
                                      + ks * 32 + fg * 8);

        f32x4 oT[8];
#pragma unroll
        for (int nd = 0; nd < 8; ++nd) oT[nd] = (f32x4){0.f, 0.f, 0.f, 0.f};
        float mrun = -1e30f, lrun = 0.f;

        const int ntiles = qt * 2 + 1 + half;
        __syncthreads();                 // prev phase's LDS reads done
        STAGE(0, 0);

        for (int t = 0; t < ntiles; ++t) {
            const int buf = t & 1;
            __syncthreads();             // drains vmcnt -> buf ready
            if (t + 1 < ntiles) STAGE(t + 1, buf ^ 1);
            const int kb = t * 64;

            if (kb <= qbase + 15) {      // wave-uniform causal skip
                f32x4 sc[4];
#pragma unroll
                for (int ni = 0; ni < 4; ++ni) sc[ni] = (f32x4){0.f, 0.f, 0.f, 0.f};
                __builtin_amdgcn_s_setprio(1);
#pragma unroll
                for (int ks = 0; ks < 4; ++ks) {
                    bf16x8 kf[4];
#pragma unroll
                    for (int ni = 0; ni < 4; ++ni) {
                        int rk = ((ni & 1) << 5) + ((fr >> 2) << 3)
                               + ((ni >> 1) << 2) + (fr & 3);
                        kf[ni] = *(const bf16x8*)&Ks[buf][rk * 128
                                     + (((ks * 4 + fg) ^ fr) * 8)];
                    }
#pragma unroll
                    for (int ni = 0; ni < 4; ++ni)
                        sc[ni] = mfma16(kf[ni], qf[ks], sc[ni]);
                }
                __builtin_amdgcn_s_setprio(0);
                const int qrow = qbase + fr;
                if (kb + 63 > qbase) {   // masking tile
#pragma unroll
                    for (int ni = 0; ni < 4; ++ni)
#pragma unroll
                        for (int j = 0; j < 4; ++j) {
                            int kcol = kb + ((ni & 1) << 5) + (fg << 3)
                                     + ((ni >> 1) << 2) + j;
                            if (kcol > qrow) sc[ni][j] = -1e30f;
                        }
                }
                float mx = sc[0][0];
#pragma unroll
                for (int ni = 0; ni < 4; ++ni)
#pragma unroll
                    for (int j = 0; j < 4; ++j) mx = fmaxf(mx, sc[ni][j]);
                mx = fmaxf(mx, __shfl_xor(mx, 16));
                mx = fmaxf(mx, __shfl_xor(mx, 32));
                if (mx > mrun) {
                    float scale = __expf(mrun - mx);
                    mrun = mx;
                    lrun *= scale;
#pragma unroll
                    for (int nd = 0; nd < 8; ++nd)
#pragma unroll
                        for (int j = 0; j < 4; ++j) oT[nd][j] *= scale;
                }
                float rs = 0.f;
                short pw[16];
#pragma unroll
                for (int ni = 0; ni < 4; ++ni)
#pragma unroll
                    for (int j = 0; j < 4; ++j) {
                        float pe = __expf(sc[ni][j] - mrun);
                        rs += pe;
                        pw[((ni & 1) << 3) + ((ni >> 1) << 2) + j] = f2bf(pe);
                    }
                bf16x8 pf0 = *(bf16x8*)&pw[0];
                bf16x8 pf1 = *(bf16x8*)&pw[8];
                rs += __shfl_xor(rs, 16);
                rs += __shfl_xor(rs, 32);
                lrun += rs;
                __builtin_amdgcn_s_setprio(1);
#pragma unroll
                for (int nd = 0; nd < 8; ++nd) {
                    const int d = nd * 16 + fr;
                    bf16x8 vf0 = *(const bf16x8*)&Vs[buf][d * 64 + ((fg ^ (d & 7)) * 8)];
                    bf16x8 vf1 = *(const bf16x8*)&Vs[buf][d * 64 + (((4 + fg) ^ (d & 7)) * 8)];
                    oT[nd] = mfma16(vf0, pf0, oT[nd]);
                    oT[nd] = mfma16(vf1, pf1, oT[nd]);
                }
                __builtin_amdgcn_s_setprio(0);
            }
        }

        float inv = 1.0f / lrun;
        int srow = qbase + fr;
#pragma unroll
        for (int nd = 0; nd < 8; ++nd) {
            s16x4 w;
#pragma unroll
            for (int j = 0; j < 4; ++j) w[j] = f2bf(oT[nd][j] * inv);
            *(s16x4*)(AO + ((size_t)b_ * S_LEN + srow) * HIDDEN
                      + h * HD + nd * 16 + fg * 4) = w;
        }
    }
#undef STAGE
#undef SWK
}

// ---------------------------------------------------------------------------
extern "C" void kernel_launch(void* const* d_in, const int* in_sizes, int n_in,
                              void* d_out, int out_size, void* d_ws, size_t ws_size,
                              hipStream_t stream)
{
    const float* hs = (const float*)d_in[0];
    const float* wq = (const float*)d_in[1];
    const float* wk = (const float*)d_in[2];
    const float* wvp = (const float*)d_in[3];
    const float* wo = (const float*)d_in[4];
    float* out = (float*)d_out;

    char* ws = (char*)d_ws;
    short* CB  = (short*)ws;
    short* Hb  = CB;
    short* Wqb = CB + 2 * (size_t)SEG;
    short* Wkb = CB + 3 * (size_t)SEG;
    short* Wvb = CB + 4 * (size_t)SEG;
    short* Wob = CB + 5 * (size_t)SEG;
    short* Qb  = (short*)(ws + 50331648);
    short* Kb  = (short*)(ws + 67108864);
    short* Vb  = (short*)(ws + 83886080);   // [bh][d][s]
    short* AO  = Hb;                         // alias: hidden dead after gemm<0>
    float* tab = (float*)(ws + 100663296);

    cast_k<<<dim3(12288), dim3(256), 0, stream>>>(hs, wq, wk, wvp, wo, CB);
    rope_table_k<<<dim3(512), dim3(256), 0, stream>>>(tab);
    gemm_bt<0><<<dim3(32, 48), dim3(256), 0, stream>>>(
        Hb, Wqb, Wkb, Wvb, Qb, Kb, Vb, nullptr, tab);
    attn_k<<<dim3(512), dim3(256), 0, stream>>>(Qb, Kb, Vb, AO);
    gemm_bt<1><<<dim3(32, 16), dim3(256), 0, stream>>>(
        AO, Wob, nullptr, nullptr, nullptr, nullptr, nullptr, out, nullptr);
}